// Round 12
// baseline (139.682 us; speedup 1.0000x reference)
//
#include <hip/hip_runtime.h>
#include <math.h>

// Dims (fixed by the problem)
#define B_SZ 2
#define L_SZ 384
#define D_SZ 384
#define S_SZ 384
#define BLK_ELEMS (L_SZ * D_SZ)        // 147456 per batch
#define TOT_ELEMS (B_SZ * L_SZ * D_SZ) // 294912
#define LOG2E 1.4426950408889634f

typedef __attribute__((ext_vector_type(8))) short bf16x8;
typedef __attribute__((ext_vector_type(4))) float f32x4;

__device__ __forceinline__ float fexp2(float x) {
  return __builtin_amdgcn_exp2f(x);
}
__device__ __forceinline__ float softplus_f(float z) {
  return (z > 20.f) ? z : log1pf(__expf(z));
}
__device__ __forceinline__ unsigned short f2bf(float f) {  // RNE f32->bf16
  unsigned int u = __float_as_uint(f);
  return (unsigned short)((u + 0x7FFFu + ((u >> 16) & 1u)) >> 16);
}
#define PIPELINE_FENCE() asm volatile("" ::: "memory")

// Async global->LDS, 16B per lane. LDS dest = wave-uniform base + lane*16
// (HW constraint — our chunk ids are laid out to conform).
__device__ __forceinline__ void g2l16(const void* g, void* l) {
  __builtin_amdgcn_global_load_lds(
      (const __attribute__((address_space(1))) unsigned int*)g,
      (__attribute__((address_space(3))) unsigned int*)l, 16, 0, 0);
}

// DPP lane exchange (VALU pipe). 0x140=row_mirror(xor15),
// 0x141=row_half_mirror(xor7), 0xB1=quad_perm[1,0,3,2](xor1).
template <int CTRL>
__device__ __forceinline__ float dpp_mov(float v) {
  return __int_as_float(
      __builtin_amdgcn_update_dpp(0, __float_as_int(v), CTRL, 0xF, 0xF, true));
}

// ---------------------------------------------------------------------------
// prep: blocks 0..719 = bf16 conversion of x/dt_w/B_w/C_w;
//       blocks 720..1007 = conv+SiLU producing u[b,l,i] and u_t[b,i,l].
// (conv no longer needs dt: scan computes dtu = dt*u inline now.)
// ---------------------------------------------------------------------------
__global__ __launch_bounds__(256) void prep_kernel(
    const float* __restrict__ x, const float* __restrict__ dt_w,
    const float* __restrict__ B_w, const float* __restrict__ C_w,
    const float* __restrict__ cw, const float* __restrict__ cb,
    unsigned short* __restrict__ xbf, unsigned short* __restrict__ dtwbf,
    unsigned short* __restrict__ Bwbf, unsigned short* __restrict__ Cwbf,
    float* __restrict__ u, float* __restrict__ u_t) {
  __shared__ float Tu[32][33];
  const int blk = blockIdx.x;
  if (blk < 720) {
    const float* src;
    unsigned short* dst;
    int base;
    if (blk < 288) { src = x; dst = xbf; base = blk; }
    else if (blk < 432) { src = dt_w; dst = dtwbf; base = blk - 288; }
    else if (blk < 576) { src = B_w; dst = Bwbf; base = blk - 432; }
    else { src = C_w; dst = Cwbf; base = blk - 576; }
    const int idx = base * 1024 + threadIdx.x * 4;
    const float4 v = *(const float4*)(src + idx);
    ushort4 o;
    o.x = f2bf(v.x); o.y = f2bf(v.y); o.z = f2bf(v.z); o.w = f2bf(v.w);
    *(ushort4*)(dst + idx) = o;
    return;
  }
  const int cblk = blk - 720;          // 0..287
  const int b = cblk / 144;
  const int rem = cblk % 144;
  const int iy = rem / 12, lx = rem % 12;
  const int tx = threadIdx.x & 31;
  const int ty = threadIdx.x >> 5;     // 0..7
  const int i0 = iy * 32, l0 = lx * 32;
  const int gi = i0 + tx;
  const float cbv = cb[gi];
  const float cw0 = cw[gi * 4 + 0], cw1 = cw[gi * 4 + 1];
  const float cw2 = cw[gi * 4 + 2], cw3 = cw[gi * 4 + 3];
#pragma unroll
  for (int r = 0; r < 4; ++r) {
    const int l = l0 + ty + 8 * r;
    float acc = cbv;
    const float x3 = x[(b * L_SZ + l) * D_SZ + gi];
    const float x2 = (l >= 1) ? x[(b * L_SZ + l - 1) * D_SZ + gi] : 0.f;
    const float x1 = (l >= 2) ? x[(b * L_SZ + l - 2) * D_SZ + gi] : 0.f;
    const float x0 = (l >= 3) ? x[(b * L_SZ + l - 3) * D_SZ + gi] : 0.f;
    acc = fmaf(x0, cw0, acc);
    acc = fmaf(x1, cw1, acc);
    acc = fmaf(x2, cw2, acc);
    acc = fmaf(x3, cw3, acc);
    const float uv = acc / (1.f + __expf(-acc));
    u[(b * L_SZ + l) * D_SZ + gi] = uv;
    Tu[ty + 8 * r][tx] = uv;
  }
  __syncthreads();
#pragma unroll
  for (int r = 0; r < 4; ++r) {
    const int il = ty + 8 * r;
    u_t[(b * D_SZ + i0 + il) * L_SZ + l0 + tx] = Tu[tx][il];
  }
}

// ---------------------------------------------------------------------------
// Dual MFMA NT-GEMM with ASYNC direct-to-LDS staging (m93->m97 ladder step:
// global_load_lds removes the 24 serialized load->ds_write round trips that
// R9-R11's staging loop paid — the invariant ~84us non-scan mass).
// Tile M=32 x N=16, 128 thr (2 waves), grid (24,24)=576. LDS contiguous
// (no pad — required by the uniform-base+lane*16 constraint).
// MODE 1: O1 = dt_t[b,i,l] = softplus(acc1+bias) TRANSPOSED scatter store;
//         O2 = xdbl bf16.
// MODE 2: O1 = Bm f32, O2 = Cm f32 (row-major [b,l,s]).
// ---------------------------------------------------------------------------
template <int MODE>
__global__ __launch_bounds__(128, 2) void mfma_dual_gemm(
    const unsigned short* __restrict__ Abf,
    const unsigned short* __restrict__ W1bf,
    const unsigned short* __restrict__ W2bf,
    const float* __restrict__ bias,
    float* __restrict__ O1, void* __restrict__ O2v) {
  __shared__ unsigned short sA[32 * 384];   // 24 KB, contiguous
  __shared__ unsigned short sW1[16 * 384];  // 12 KB
  __shared__ unsigned short sW2[16 * 384];  // 12 KB

  const int t = threadIdx.x;      // 0..127
  const int wv = t >> 6;
  const int lane = t & 63;
  const int nt = blockIdx.x;      // 0..23
  const int mrow = blockIdx.y;    // 0..23

  const unsigned short* Ab = Abf + mrow * 32 * 384;
  const unsigned short* W1b = W1bf + nt * 16 * 384;
  const unsigned short* W2b = W2bf + nt * 16 * 384;

  // A: 1536 16B-chunks, 12/thread; W: 768 chunks, 6/thread each.
#pragma unroll
  for (int it = 0; it < 12; ++it) {
    const int id = t + it * 128;
    g2l16(Ab + id * 8, (char*)sA + id * 16);
  }
#pragma unroll
  for (int it = 0; it < 6; ++it) {
    const int id = t + it * 128;
    g2l16(W1b + id * 8, (char*)sW1 + id * 16);
    g2l16(W2b + id * 8, (char*)sW2 + id * 16);
  }
  __syncthreads();  // compiler emits s_waitcnt vmcnt(0) before s_barrier

  const int rc = lane & 15;
  const int quad = lane >> 4;
  bf16x8 af[12], w1f[12], w2f[12];
#pragma unroll
  for (int kt = 0; kt < 12; ++kt) {
    af[kt] = *(const bf16x8*)&sA[(wv * 16 + rc) * 384 + kt * 32 + quad * 8];
    w1f[kt] = *(const bf16x8*)&sW1[rc * 384 + kt * 32 + quad * 8];
    w2f[kt] = *(const bf16x8*)&sW2[rc * 384 + kt * 32 + quad * 8];
  }
  PIPELINE_FENCE();
  f32x4 acc1 = {0.f, 0.f, 0.f, 0.f};
  f32x4 acc2 = {0.f, 0.f, 0.f, 0.f};
#pragma unroll
  for (int kt = 0; kt < 12; ++kt) {
    acc1 = __builtin_amdgcn_mfma_f32_16x16x32_bf16(af[kt], w1f[kt], acc1, 0, 0, 0);
    acc2 = __builtin_amdgcn_mfma_f32_16x16x32_bf16(af[kt], w2f[kt], acc2, 0, 0, 0);
  }
  const int col = nt * 16 + rc;               // output column (i or s)
  const int row0 = mrow * 32 + wv * 16 + quad * 4;  // output row (b*L + l)
  if constexpr (MODE == 1) {
    unsigned short* O2 = (unsigned short*)O2v;
    const float bb = bias[col];
    const int b = row0 / L_SZ;
    const int lb = row0 - b * L_SZ;
#pragma unroll
    for (int r = 0; r < 4; ++r) {
      // dt_t[b, i=col, l=lb+r] — transposed scatter (64 lines/wave, cheap)
      O1[(b * D_SZ + col) * L_SZ + lb + r] = softplus_f(acc1[r] + bb);
      O2[(row0 + r) * 384 + col] = f2bf(acc2[r]);
    }
  } else {
    float* O2 = (float*)O2v;
#pragma unroll
    for (int r = 0; r < 4; ++r) {
      O1[(row0 + r) * 384 + col] = acc1[r];
      O2[(row0 + r) * 384 + col] = acc2[r];
    }
  }
}

// ---------------------------------------------------------------------------
// Selective scan v11 (structure kept from R11): Tc=1, 6-way j-split,
// 4608 waves, asm-pinned loads + vmcnt(24), DPP fold. Change: loads u_t
// instead of dtu_t and computes dtu = dt*u inline (+1 mul/step).
// ---------------------------------------------------------------------------
struct ChunkS {
  f32x4 d0, d1, u0, u1;
  float c[8];
};

#define LOAD_CHUNK(K, B0, B1, B2, DTB, DUB)                                    \
  {                                                                            \
    asm volatile("global_load_dwordx4 %0, %1, off" : "=v"(K.d0) : "v"(DTB));   \
    asm volatile("global_load_dwordx4 %0, %1, off offset:16"                   \
                 : "=v"(K.d1) : "v"(DTB));                                     \
    asm volatile("global_load_dwordx4 %0, %1, off" : "=v"(K.u0) : "v"(DUB));   \
    asm volatile("global_load_dwordx4 %0, %1, off offset:16"                   \
                 : "=v"(K.u1) : "v"(DUB));                                     \
    asm volatile("global_load_dword %0, %1, off" : "=v"(K.c[0]) : "v"(B0));    \
    asm volatile("global_load_dword %0, %1, off offset:1536"                   \
                 : "=v"(K.c[1]) : "v"(B0));                                    \
    asm volatile("global_load_dword %0, %1, off offset:3072"                   \
                 : "=v"(K.c[2]) : "v"(B0));                                    \
    asm volatile("global_load_dword %0, %1, off" : "=v"(K.c[3]) : "v"(B1));    \
    asm volatile("global_load_dword %0, %1, off offset:1536"                   \
                 : "=v"(K.c[4]) : "v"(B1));                                    \
    asm volatile("global_load_dword %0, %1, off offset:3072"                   \
                 : "=v"(K.c[5]) : "v"(B1));                                    \
    asm volatile("global_load_dword %0, %1, off" : "=v"(K.c[6]) : "v"(B2));    \
    asm volatile("global_load_dword %0, %1, off offset:1536"                   \
                 : "=v"(K.c[7]) : "v"(B2));                                    \
  }

#define WAIT_CHUNK(K)                                                          \
  asm volatile("s_waitcnt vmcnt(24)"                                           \
               : "+v"(K.d0), "+v"(K.d1), "+v"(K.u0), "+v"(K.u1),               \
                 "+v"(K.c[0]), "+v"(K.c[1]), "+v"(K.c[2]), "+v"(K.c[3]),       \
                 "+v"(K.c[4]), "+v"(K.c[5]), "+v"(K.c[6]), "+v"(K.c[7]))

#define ADV_BASES()                                                            \
  { cb0 += 3072; cb1 += 3072; cb2 += 3072; dtB += 8; duB += 8; }

__global__ __launch_bounds__(64, 4) void scan_kernel(
    const float* __restrict__ A_log, const float* __restrict__ dt_t,
    const float* __restrict__ u_t, const float* __restrict__ Bm,
    const float* __restrict__ Cm, float* __restrict__ part) {
  const int wave = blockIdx.x;       // 0..4607
  const int lane = threadIdx.x;      // 0..63
  const int w = wave % 6;
  const int sid = wave / 6;
  const int b = sid / D_SZ;
  const int i = sid % D_SZ;
  const int j = w * 64 + lane;

  const float a2 = -__expf(A_log[i * S_SZ + j]) * LOG2E;
  const float bw = Bm[(b * D_SZ + i) * S_SZ + j];
  float h = 0.f;

  const float* dtB = dt_t + (b * D_SZ + i) * L_SZ;
  const float* duB = u_t + (b * D_SZ + i) * L_SZ;
  const float* cmrow = Cm + b * BLK_ELEMS + j;
  const float* cb0 = cmrow;
  const float* cb1 = cmrow + 3 * D_SZ;
  const float* cb2 = cmrow + 6 * D_SZ;

  const int sq = (((lane >> 3) & 1) << 2) | (((lane >> 2) & 1) << 1) | (lane & 1);
  const bool storer = (lane & 0x32) == 0;
  float* pstore = part + ((w * B_SZ + b) * D_SZ + i) * L_SZ + sq;

  asm volatile("" :: "v"(a2), "v"(bw));
  asm volatile("s_waitcnt vmcnt(0)");

  auto compute_chunk = [&](ChunkS& K) {
    float acc[8];
    const float dts[8] = {K.d0[0], K.d0[1], K.d0[2], K.d0[3],
                          K.d1[0], K.d1[1], K.d1[2], K.d1[3]};
    const float us[8] = {K.u0[0], K.u0[1], K.u0[2], K.u0[3],
                         K.u1[0], K.u1[1], K.u1[2], K.u1[3]};
#pragma unroll
    for (int s = 0; s < 8; ++s) {
      const float e = fexp2(dts[s] * a2);
      h = fmaf(e, h, bw * (dts[s] * us[s]));
      acc[s] = h * K.c[s];
    }
    {
      const bool hi = (lane & 8) != 0;
#pragma unroll
      for (int q = 0; q < 4; ++q) {
        const float keep = hi ? acc[q + 4] : acc[q];
        const float send = hi ? acc[q] : acc[q + 4];
        acc[q] = keep + dpp_mov<0x140>(send);
      }
    }
    {
      const bool hi = (lane & 4) != 0;
#pragma unroll
      for (int q = 0; q < 2; ++q) {
        const float keep = hi ? acc[q + 2] : acc[q];
        const float send = hi ? acc[q] : acc[q + 2];
        acc[q] = keep + dpp_mov<0x141>(send);
      }
    }
    {
      const bool hi = (lane & 1) != 0;
      const float keep = hi ? acc[1] : acc[0];
      const float send = hi ? acc[0] : acc[1];
      acc[0] = keep + dpp_mov<0xB1>(send);
    }
    float r = acc[0];
    r += __shfl_xor(r, 2, 64);
    r += __shfl_xor(r, 16, 64);
    r += __shfl_xor(r, 32, 64);
    if (storer) *pstore = r;
    pstore += 8;
  };

  ChunkS K0, K1, K2;
  LOAD_CHUNK(K0, cb0, cb1, cb2, dtB, duB);
  ADV_BASES();
  LOAD_CHUNK(K1, cb0, cb1, cb2, dtB, duB);
  ADV_BASES();
#pragma unroll 1
  for (int it = 0; it < 16; ++it) {
    LOAD_CHUNK(K2, cb0, cb1, cb2, dtB, duB);
    ADV_BASES();
    WAIT_CHUNK(K0);
    compute_chunk(K0);
    LOAD_CHUNK(K0, cb0, cb1, cb2, dtB, duB);
    ADV_BASES();
    WAIT_CHUNK(K1);
    compute_chunk(K1);
    LOAD_CHUNK(K1, cb0, cb1, cb2, dtB, duB);
    ADV_BASES();
    WAIT_CHUNK(K2);
    compute_chunk(K2);
  }
  // 48 chunks computed; 2 extra prefetches read harmlessly into adjacent ws.
}

// ---------------------------------------------------------------------------
// Combine + transpose: y[b,l,i] = sum_{w<6} part[w][b][i][l] + u[b,l,i]*D[i]
// ---------------------------------------------------------------------------
__global__ __launch_bounds__(256) void combine_kernel(
    const float* __restrict__ part, const float* __restrict__ u,
    const float* __restrict__ Dv, float* __restrict__ y) {
  __shared__ float T[32][33];
  const int tx = threadIdx.x;
  const int ty0 = threadIdx.y;
  const int b = blockIdx.z;
  const int i0 = blockIdx.y * 32;
  const int l0 = blockIdx.x * 32;
#pragma unroll
  for (int r = 0; r < 4; ++r) {
    const int il = ty0 + 8 * r;
    float s = 0.f;
#pragma unroll
    for (int w = 0; w < 6; ++w)
      s += part[((w * B_SZ + b) * D_SZ + i0 + il) * L_SZ + l0 + tx];
    T[il][tx] = s;
  }
  __syncthreads();
#pragma unroll
  for (int r = 0; r < 4; ++r) {
    const int ll = ty0 + 8 * r;
    const int gi = i0 + tx;
    const int off = (b * L_SZ + l0 + ll) * D_SZ + gi;
    y[off] = fmaf(u[off], Dv[gi], T[tx][ll]);
  }
}

extern "C" void kernel_launch(void* const* d_in, const int* in_sizes, int n_in,
                              void* d_out, int out_size, void* d_ws,
                              size_t ws_size, hipStream_t stream) {
  const float* x = (const float*)d_in[0];
  const float* A_log = (const float*)d_in[1];
  const float* D = (const float*)d_in[2];
  const float* dt_w = (const float*)d_in[3];
  const float* dt_b = (const float*)d_in[4];
  const float* B_w = (const float*)d_in[5];
  const float* C_w = (const float*)d_in[6];
  const float* conv_w = (const float*)d_in[7];
  const float* conv_b = (const float*)d_in[8];
  float* y = (float*)d_out;

  float* ws = (float*)d_ws;
  float* u = ws;                      // slot 0  [b,l,i]
  float* Bm = ws + TOT_ELEMS;         // slot 1
  float* Cm = ws + 2 * TOT_ELEMS;     // slot 2
  float* dt_t = ws + 3 * TOT_ELEMS;   // slot 3  [b,i,l] (written by GEMM1)
  float* u_t = ws + 4 * TOT_ELEMS;    // slot 4  [b,i,l]
  float* part = ws + 5 * TOT_ELEMS;   // slots 5..10  [w][b][i][l], w<6
  unsigned short* bfarea = (unsigned short*)(ws + 11 * TOT_ELEMS);
  unsigned short* xbf = bfarea;                 // 294912
  unsigned short* dtwbf = bfarea + 294912;      // 147456
  unsigned short* Bwbf = bfarea + 442368;       // 147456
  unsigned short* Cwbf = bfarea + 589824;       // 147456
  unsigned short* xdblbf = bfarea + 737280;     // 294912

  prep_kernel<<<1008, 256, 0, stream>>>(x, dt_w, B_w, C_w, conv_w, conv_b,
                                        xbf, dtwbf, Bwbf, Cwbf, u, u_t);
  mfma_dual_gemm<1><<<dim3(24, 24), 128, 0, stream>>>(xbf, dtwbf, Bwbf, dt_b,
                                                      dt_t, xdblbf);
  mfma_dual_gemm<2><<<dim3(24, 24), 128, 0, stream>>>(xdblbf, Bwbf, Cwbf,
                                                      nullptr, Bm, Cm);
  scan_kernel<<<6 * B_SZ * D_SZ, 64, 0, stream>>>(A_log, dt_t, u_t, Bm, Cm, part);
  combine_kernel<<<dim3(L_SZ / 32, D_SZ / 32, B_SZ), dim3(32, 8), 0, stream>>>(
      part, u, D, y);
}